// Round 3
// baseline (4664.083 us; speedup 1.0000x reference)
//
#include <hip/hip_runtime.h>
#include <cstdint>
#include <cstddef>

#define H 1024
#define SEQ 512
#define THREEH 3072
#define VOCABN 32000
#define NBLK 64      // recurrence blocks (block = 16 h-indices)
#define NWORK 192    // worker blocks (gxe+gxd GEMM, LLC warm, projection)
#define HPB 16       // h-indices per rnn block

// h strictly in (-1,1); transport stores h+2 in (1,3). Flags store 1.0.
// Anything <= 0.5 (0xAA poison = -3e-13, NaN, zeros) means "not written".
#define HBIAS 2.0f
#define HVALID 0.5f

// ---------- 16-lane row reduction: pure VALU DPP, no DS ops ----------
template <int CTRL>
__device__ __forceinline__ float dpp_add(float v) {
    return v + __int_as_float(__builtin_amdgcn_update_dpp(
        0, __float_as_int(v), CTRL, 0xF, 0xF, true));
}
__device__ __forceinline__ float row16_sum(float v) {
    v = dpp_add<0xB1>(v);    // quad_perm [1,0,3,2]  (xor 1)
    v = dpp_add<0x4E>(v);    // quad_perm [2,3,0,1]  (xor 2)
    v = dpp_add<0x124>(v);   // row_ror:4
    v = dpp_add<0x128>(v);   // row_ror:8
    return v;                // all 16 lanes of the row hold the sum
}

// ---------- recurrence path: blocks 0..63 ----------
// Wave w owns h-indices i0+4w..i0+4w+3; group g (lane>>4) handles index
// i0+4w+g, lane p (lane&15) covers h-columns [64p,64p+64) for all 3
// gates. Transport sync is a compact per-block flag row tf[step][64]:
// producers drain data stores at a barrier then set tf[step][blk]; the
// consumer's wave 0 polls ONLY the 256B flag row (2 LLC lines) instead
// of the 4KB data row, then all waves do ONE atomic read round of the
// data. This removes the LLC hot-line queueing of data-as-flag polling.
__device__ void rnn_path(int blk, int tid, float* smem,
    const float* __restrict__ eWhh, const float* __restrict__ ebhh,
    const float* __restrict__ dWhh, const float* __restrict__ dbhh,
    const float* __restrict__ gxe, const float* __restrict__ gxd,
    float* __restrict__ enc_t, float* __restrict__ dec_t,
    float* __restrict__ tf,
    const float* __restrict__ fe, const float* __restrict__ fd)
{
    const int wave = tid >> 6;
    const int lane = tid & 63;
    const int g = lane >> 4;       // h-index offset within the wave
    const int p = lane & 15;       // 64-column slice owner
    const int i0 = blk * HPB;
    const int myidx = i0 + 4 * wave + g;

    float* hb = smem;              // [H] biased-h broadcast (single buffer:
                                   // writes A->B, reads B->C, barrier-safe)

    float4 wreg[3][16];            // [gate][k] = W[gate*H+myidx][64p+4*((k+p)&15)..]
    float br, bz, bn;              // biases with -HBIAS*rowsum(W) folded in
    float hown = 0.f;

    auto load_w = [&](const float* __restrict__ W, const float* __restrict__ b) {
        float ws[3];
#pragma unroll
        for (int gate = 0; gate < 3; ++gate) {
            const float* base = W + (size_t)(gate * H + myidx) * H + 64 * p;
            float s = 0.f;
#pragma unroll
            for (int k = 0; k < 16; ++k) {
                float4 w = *(const float4*)(base + 4 * ((k + p) & 15));
                wreg[gate][k] = w;
                s += w.x + w.y + w.z + w.w;
            }
            ws[gate] = s;
        }
        br = b[myidx]         - HBIAS * row16_sum(ws[0]);
        bz = b[H + myidx]     - HBIAS * row16_sum(ws[1]);
        bn = b[2 * H + myidx] - HBIAS * row16_sum(ws[2]);
    };

    load_w(eWhh, ebhh);

    for (int step = 0; step < 2 * SEQ; ++step) {
        const bool dec = step >= SEQ;
        const int t = dec ? step - SEQ : step;
        if (dec && t == 0) load_w(dWhh, dbhh);

        // --- gx m-block gate (once per 64 steps; pre-satisfied after warmup)
        if ((t & 63) == 0) {
            const float* fl = (dec ? fd : fe) + (t >> 6) * 64
                              + (lane < 48 ? lane : 47);
            for (;;) {
                float f = __hip_atomic_load(fl,
                    __ATOMIC_RELAXED, __HIP_MEMORY_SCOPE_AGENT);
                if (__all(f > HVALID)) break;
                __builtin_amdgcn_s_sleep(4);
            }
        }

        const float* gx = dec ? gxd : gxe;
        float* tb_out = (dec ? dec_t : enc_t) + (size_t)t * H;

        // gx prefetch (relaxed agent atomics: LLC-direct, no fence needed;
        // issued early, consumed after the reductions)
        const float* gxp = gx + (size_t)t * THREEH + myidx;
        float gxr = __hip_atomic_load(gxp,
            __ATOMIC_RELAXED, __HIP_MEMORY_SCOPE_AGENT);
        float gxz = __hip_atomic_load(gxp + H,
            __ATOMIC_RELAXED, __HIP_MEMORY_SCOPE_AGENT);
        float gxn = __hip_atomic_load(gxp + 2 * H,
            __ATOMIC_RELAXED, __HIP_MEMORY_SCOPE_AGENT);

        // --- flag poll: wave 0 only, 256B row, tight loop (rnn CU is ours)
        if (step > 0 && wave == 0) {
            const float* fl = tf + (size_t)(step - 1) * 64 + lane;
            for (;;) {
                float f = __hip_atomic_load(fl,
                    __ATOMIC_RELAXED, __HIP_MEMORY_SCOPE_AGENT);
                if (__all(f > HVALID)) break;
            }
        }
        __syncthreads();   // A: detection published to all waves

        // --- single-shot data read round (biased values straight to LDS)
        if (step == 0) {
            *(float4*)&hb[tid * 4] = float4{HBIAS, HBIAS, HBIAS, HBIAS};
        } else {
            const float* tb_prev =
                (step <= SEQ) ? enc_t + (size_t)(step - 1) * H
                              : dec_t + (size_t)(step - SEQ - 1) * H;
            const unsigned long long* src =
                (const unsigned long long*)tb_prev + wave * 128 + lane * 2;
            union { unsigned long long u; float f[2]; } cv[2];
            cv[0].u = __hip_atomic_load(src,
                __ATOMIC_RELAXED, __HIP_MEMORY_SCOPE_AGENT);
            cv[1].u = __hip_atomic_load(src + 1,
                __ATOMIC_RELAXED, __HIP_MEMORY_SCOPE_AGENT);
            *(float4*)&hb[wave * 256 + lane * 4] =
                float4{cv[0].f[0], cv[0].f[1], cv[1].f[0], cv[1].f[1]};
        }
        __syncthreads();   // B: LDS h ready

        // dot products over the biased h; rotation keeps register indices
        // compile-time and LDS reads at worst 2-way conflicted (free).
        float a0 = 0.f, a1 = 0.f, a2 = 0.f;
#pragma unroll
        for (int k = 0; k < 16; ++k) {
            float4 h = *(const float4*)&hb[64 * p + 4 * ((k + p) & 15)];
            float4 w0 = wreg[0][k], w1 = wreg[1][k], w2 = wreg[2][k];
            a0 += w0.x * h.x + w0.y * h.y + w0.z * h.z + w0.w * h.w;
            a1 += w1.x * h.x + w1.y * h.y + w1.z * h.z + w1.w * h.w;
            a2 += w2.x * h.x + w2.y * h.y + w2.z * h.z + w2.w * h.w;
        }
        float sr = row16_sum(a0);
        float sz = row16_sum(a1);
        float sn = row16_sum(a2);

        float rg = 1.f / (1.f + expf(-(gxr + sr + br)));
        float zg = 1.f / (1.f + expf(-(gxz + sz + bz)));
        float ng = tanhf(gxn + rg * (sn + bn));
        float hnew = (1.f - zg) * ng + zg * hown;
        hown = hnew;

        if (p == 0)
            __hip_atomic_store(tb_out + myidx, hnew + HBIAS,
                               __ATOMIC_RELAXED, __HIP_MEMORY_SCOPE_AGENT);
        __syncthreads();   // C: every wave's stores drained (vmcnt 0 at barrier)
        if (tid == 0)
            __hip_atomic_store(tf + (size_t)step * 64 + blk, 1.0f,
                               __ATOMIC_RELAXED, __HIP_MEMORY_SCOPE_AGENT);
    }
}

// ---------- worker GEMM tile (64x64, TK=16) ----------
// MODE 0: A = emb[inputs[m]]            (encoder input GEMM -> gxe)
// MODE 1: A = emb[m==0?0:targets[m-1]]  (decoder input GEMM -> gxd)
// MODE 2: A = dec_t[m] - HBIAS          (projection -> logits)
template <int MODE>
__device__ void gemm_tile(const float* __restrict__ Abase,
                          const int* __restrict__ toks,
                          int m0, int n0,
                          const float* __restrict__ W,
                          const float* __restrict__ bias,
                          float* __restrict__ C, int N,
                          float* __restrict__ sA, float* __restrict__ sB)
{
    const int tid = threadIdx.x;
    const int r = tid >> 2;
    const int c = tid & 3;
    const int tx = tid & 15;
    const int ty = tid >> 4;
    const int m = m0 + r;

    const float* Arow;
    if (MODE == 0)      Arow = Abase + (size_t)toks[m] * H;
    else if (MODE == 1) Arow = Abase + (size_t)(m == 0 ? 0 : toks[m - 1]) * H;
    else                Arow = Abase + (size_t)m * H;
    const float* Brow = W + (size_t)(n0 + r) * H;
    const float abias = (MODE == 2) ? HBIAS : 0.f;

    float acc[4][4] = {};
    for (int k0 = 0; k0 < H; k0 += 16) {
        float4 av = *(const float4*)(Arow + k0 + c * 4);
        float4 bv = *(const float4*)(Brow + k0 + c * 4);
        __syncthreads();
        sA[(c * 4 + 0) * 68 + r] = av.x - abias;
        sA[(c * 4 + 1) * 68 + r] = av.y - abias;
        sA[(c * 4 + 2) * 68 + r] = av.z - abias;
        sA[(c * 4 + 3) * 68 + r] = av.w - abias;
        sB[(c * 4 + 0) * 68 + r] = bv.x;
        sB[(c * 4 + 1) * 68 + r] = bv.y;
        sB[(c * 4 + 2) * 68 + r] = bv.z;
        sB[(c * 4 + 3) * 68 + r] = bv.w;
        __syncthreads();
#pragma unroll
        for (int kk = 0; kk < 16; ++kk) {
            float4 a = *(const float4*)&sA[kk * 68 + ty * 4];
            float4 b = *(const float4*)&sB[kk * 68 + tx * 4];
            float avv[4] = {a.x, a.y, a.z, a.w};
            float bvv[4] = {b.x, b.y, b.z, b.w};
#pragma unroll
            for (int i = 0; i < 4; ++i)
#pragma unroll
                for (int jj = 0; jj < 4; ++jj)
                    acc[i][jj] += avv[i] * bvv[jj];
        }
    }
    float4 bq = *(const float4*)(bias + n0 + tx * 4);
    float bb[4] = {bq.x, bq.y, bq.z, bq.w};
#pragma unroll
    for (int i = 0; i < 4; ++i) {
        float4 o;
        o.x = acc[i][0] + bb[0];
        o.y = acc[i][1] + bb[1];
        o.z = acc[i][2] + bb[2];
        o.w = acc[i][3] + bb[3];
        *(float4*)&C[(size_t)(m0 + ty * 4 + i) * N + n0 + tx * 4] = o;
    }
}

// ---------- worker path: blocks 64..255 ----------
// Producer phases run UNCONDITIONALLY first (acyclic: workers -> gx -> rnn,
// rnn -> dec_t -> workers; all 256 blocks co-resident at 1/CU).
// Phase gxe/gxd: tiles in mb-major order; after each tile, __threadfence()
// (L2 writeback) then a per-tile flag store. rnn gates on the 48 flags of
// each 64-row m-block and reads gx via LLC-direct atomics.
// Phase warm: touch pW so projection's first pass hits LLC.
// Phase proj: round-2's data-as-flag gating on dec_t (proven).
__device__ void worker_path(int wid, int tid, float* smem,
    const float* __restrict__ emb,
    const int* __restrict__ inputs, const int* __restrict__ targets,
    const float* __restrict__ eWih, const float* __restrict__ ebih,
    const float* __restrict__ dWih, const float* __restrict__ dbih,
    float* __restrict__ gxe, float* __restrict__ gxd,
    float* __restrict__ fe, float* __restrict__ fd,
    const float* __restrict__ dec_t,
    const float* __restrict__ pW, const float* __restrict__ pb,
    float* __restrict__ out)
{
    float* sA = smem;
    float* sB = smem + 16 * 68;

    // Phase gxe: 8 x 48 tiles, mb-major so early m-blocks complete first
    for (int q = wid; q < 8 * 48; q += NWORK) {
        int mb = q / 48, nb = q % 48;
        gemm_tile<0>(emb, inputs, mb * 64, nb * 64, eWih, ebih,
                     gxe, THREEH, sA, sB);
        __threadfence();   // push tile stores through L2 to LLC
        __syncthreads();   // all waves' stores fenced before flag
        if (tid == 0)
            __hip_atomic_store(fe + mb * 64 + nb, 1.0f,
                               __ATOMIC_RELAXED, __HIP_MEMORY_SCOPE_AGENT);
    }
    // Phase gxd: same for the decoder input GEMM
    for (int q = wid; q < 8 * 48; q += NWORK) {
        int mb = q / 48, nb = q % 48;
        gemm_tile<1>(emb, targets, mb * 64, nb * 64, dWih, dbih,
                     gxd, THREEH, sA, sB);
        __threadfence();
        __syncthreads();
        if (tid == 0)
            __hip_atomic_store(fd + mb * 64 + nb, 1.0f,
                               __ATOMIC_RELAXED, __HIP_MEMORY_SCOPE_AGENT);
    }

    // Phase warm: touch one dword per 128B line of pW
    {
        float acc = 0.f;
        const size_t nlines = (size_t)VOCABN * H / 32;   // 1,024,000
        for (size_t i = (size_t)wid * 256 + tid; i < nlines;
             i += (size_t)NWORK * 256)
            acc += pW[i * 32];
        asm volatile("" :: "v"(acc));   // keep the loads alive (no DCE)
    }

    // Phase proj: logits = (dec_t - HBIAS) @ pW^T + pb   (8 x 500 tiles)
    int cur = -1;
    for (int tt = wid; tt < 8 * 500; tt += NWORK) {
        int mb = tt / 500, nb = tt % 500;
        if (mb != cur) {
            if (tid < 64) {
                const unsigned long long* src =
                    (const unsigned long long*)(dec_t + (size_t)(mb * 64 + 63) * H);
                for (;;) {
                    bool ok = true;
#pragma unroll
                    for (int m = 0; m < 8; ++m) {
                        union { unsigned long long u; float f[2]; } c;
                        c.u = __hip_atomic_load(src + tid + 64 * m,
                            __ATOMIC_RELAXED, __HIP_MEMORY_SCOPE_AGENT);
                        ok &= (c.f[0] > HVALID) & (c.f[1] > HVALID);
                    }
                    if (ok) break;
                    __builtin_amdgcn_s_sleep(64);   // coarse: slack is large
                }
            }
            __syncthreads();
            __builtin_amdgcn_fence(__ATOMIC_ACQUIRE, "agent"); // drop stale L1/L2
            cur = mb;
        }
        gemm_tile<2>(dec_t, nullptr, mb * 64, nb * 64, pW, pb,
                     out, VOCABN, sA, sB);
    }
}

// ---------- fused persistent kernel: 64 rnn blocks + 192 workers ----------
__global__ __launch_bounds__(256, 1) void fused_rnn(
    const float* __restrict__ eWhh, const float* __restrict__ ebhh,
    const float* __restrict__ dWhh, const float* __restrict__ dbhh,
    float* __restrict__ gxe, float* __restrict__ gxd,
    float* __restrict__ enc_t, float* __restrict__ dec_t,
    float* __restrict__ tf, float* __restrict__ fe, float* __restrict__ fd,
    const float* __restrict__ emb,
    const int* __restrict__ inputs, const int* __restrict__ targets,
    const float* __restrict__ eWih, const float* __restrict__ ebih,
    const float* __restrict__ dWih, const float* __restrict__ dbih,
    const float* __restrict__ pW, const float* __restrict__ pb,
    float* __restrict__ out)
{
    __shared__ float smem[2176];   // rnn: hb[1024]; worker: sA/sB [16][68]
    const int b = blockIdx.x;
    if (b < NBLK)
        rnn_path(b, threadIdx.x, smem, eWhh, ebhh, dWhh, dbhh,
                 gxe, gxd, enc_t, dec_t, tf, fe, fd);
    else
        worker_path(b - NBLK, threadIdx.x, smem, emb, inputs, targets,
                    eWih, ebih, dWih, dbih, gxe, gxd, fe, fd,
                    dec_t, pW, pb, out);
}

extern "C" void kernel_launch(void* const* d_in, const int* in_sizes, int n_in,
                              void* d_out, int out_size, void* d_ws, size_t ws_size,
                              hipStream_t stream) {
    const int*   inputs  = (const int*)d_in[0];
    const int*   targets = (const int*)d_in[1];
    const float* emb     = (const float*)d_in[2];
    const float* eWih    = (const float*)d_in[3];
    const float* eWhh    = (const float*)d_in[4];
    const float* ebih    = (const float*)d_in[5];
    const float* ebhh    = (const float*)d_in[6];
    const float* dWih    = (const float*)d_in[7];
    const float* dWhh    = (const float*)d_in[8];
    const float* dbih    = (const float*)d_in[9];
    const float* dbhh    = (const float*)d_in[10];
    const float* pW      = (const float*)d_in[11];
    const float* pb      = (const float*)d_in[12];
    float* out = (float*)d_out;

    float* gxe   = (float*)d_ws;                  // [512][3072]
    float* gxd   = gxe + (size_t)SEQ * THREEH;    // [512][3072]
    float* enc_t = gxd + (size_t)SEQ * THREEH;    // [512][1024] biased
    float* dec_t = enc_t + (size_t)SEQ * H;       // [512][1024] biased
    float* tf    = dec_t + (size_t)SEQ * H;       // [1024][64] transport flags
    float* fe    = tf + (size_t)2 * SEQ * 64;     // [8][64] gxe tile flags
    float* fd    = fe + 8 * 64;                   // [8][64] gxd tile flags

    // single fused launch: 64 recurrence blocks + 192 GEMM workers
    fused_rnn<<<NBLK + NWORK, 256, 0, stream>>>(
        eWhh, ebhh, dWhh, dbhh, gxe, gxd, enc_t, dec_t, tf, fe, fd,
        emb, inputs, targets, eWih, ebih, dWih, dbih, pW, pb, out);
}

// Round 4
// 3727.194 us; speedup vs baseline: 1.2514x; 1.2514x over previous
//
#include <hip/hip_runtime.h>
#include <cstdint>
#include <cstddef>

#define H 1024
#define SEQ 512
#define THREEH 3072
#define VOCABN 32000
#define NBLK 64      // recurrence blocks (block = 16 h-indices)
#define NWORK 192    // worker blocks (gxe+gxd GEMM, LLC warm, projection)
#define HPB 16       // h-indices per rnn block

// h strictly in (-1,1); transport stores h+2 in (1,3). Flags store 1.0.
// Anything <= 0.5 (0xAA poison = -3e-13, NaN, zeros) means "not written".
#define HBIAS 2.0f
#define HVALID 0.5f

// ---------- 16-lane row reduction: pure VALU DPP, no DS ops ----------
template <int CTRL>
__device__ __forceinline__ float dpp_add(float v) {
    return v + __int_as_float(__builtin_amdgcn_update_dpp(
        0, __float_as_int(v), CTRL, 0xF, 0xF, true));
}
__device__ __forceinline__ float row16_sum(float v) {
    v = dpp_add<0xB1>(v);    // quad_perm [1,0,3,2]  (xor 1)
    v = dpp_add<0x4E>(v);    // quad_perm [2,3,0,1]  (xor 2)
    v = dpp_add<0x124>(v);   // row_ror:4
    v = dpp_add<0x128>(v);   // row_ror:8
    return v;                // all 16 lanes of the row hold the sum
}

// ---------- recurrence path: blocks 0..63 ----------
// Round-2 transport (proven 3.3us/step): data-as-flag — every wave polls
// its OWN quarter of the previous transport row directly (coalesced 8B
// atomic loads), writes it to double-buffered LDS, ONE barrier, compute,
// fire-and-forget atomic h store. No flag indirection (round 3 showed
// that costs +2 serial LLC hops/step). gx comes from in-kernel workers,
// gated once per 64 steps on fe/fd tile flags + acquire fence, then read
// with plain cached loads.
__device__ void rnn_path(int blk, int tid, float* smem,
    const float* __restrict__ eWhh, const float* __restrict__ ebhh,
    const float* __restrict__ dWhh, const float* __restrict__ dbhh,
    const float* __restrict__ gxe, const float* __restrict__ gxd,
    float* __restrict__ enc_t, float* __restrict__ dec_t,
    const float* __restrict__ fe, const float* __restrict__ fd)
{
    const int wave = tid >> 6;
    const int lane = tid & 63;
    const int g = lane >> 4;       // h-index offset within the wave
    const int p = lane & 15;       // 64-column slice owner
    const int i0 = blk * HPB;
    const int myidx = i0 + 4 * wave + g;

    float* hs0 = smem;             // [H] double-buffered biased-h broadcast
    float* hs1 = smem + H;

    float4 wreg[3][16];            // [gate][k] = W[gate*H+myidx][64p+4*((k+p)&15)..]
    float br, bz, bn;              // biases with -HBIAS*rowsum(W) folded in
    float hown = 0.f;

    auto load_w = [&](const float* __restrict__ W, const float* __restrict__ b) {
        float ws[3];
#pragma unroll
        for (int gate = 0; gate < 3; ++gate) {
            const float* base = W + (size_t)(gate * H + myidx) * H + 64 * p;
            float s = 0.f;
#pragma unroll
            for (int k = 0; k < 16; ++k) {
                float4 w = *(const float4*)(base + 4 * ((k + p) & 15));
                wreg[gate][k] = w;
                s += w.x + w.y + w.z + w.w;
            }
            ws[gate] = s;
        }
        br = b[myidx]         - HBIAS * row16_sum(ws[0]);
        bz = b[H + myidx]     - HBIAS * row16_sum(ws[1]);
        bn = b[2 * H + myidx] - HBIAS * row16_sum(ws[2]);
    };

    load_w(eWhh, ebhh);

    for (int step = 0; step < 2 * SEQ; ++step) {
        const bool dec = step >= SEQ;
        const int t = dec ? step - SEQ : step;
        if (dec && t == 0) load_w(dWhh, dbhh);

        // --- gx m-block gate (once per 64 steps; pre-satisfied after warmup)
        if ((t & 63) == 0) {
            const float* fl = (dec ? fd : fe) + (t >> 6) * 64
                              + (lane < 48 ? lane : 47);
            for (;;) {
                float f = __hip_atomic_load(fl,
                    __ATOMIC_RELAXED, __HIP_MEMORY_SCOPE_AGENT);
                if (__all(f > HVALID)) break;
                __builtin_amdgcn_s_sleep(4);
            }
            // release (workers: __threadfence) / acquire pair: drop any
            // stale L1/L2 lines before plain cached gx loads below.
            __builtin_amdgcn_fence(__ATOMIC_ACQUIRE, "agent");
        }

        const float* gx = dec ? gxd : gxe;
        float* tb_out = (dec ? dec_t : enc_t) + (size_t)t * H;
        float* hb = (step & 1) ? hs1 : hs0;

        // gx prefetch (plain cached loads, issued before the poll,
        // consumed after the reductions)
        const float* gxp = gx + (size_t)t * THREEH + myidx;
        float gxr = gxp[0];
        float gxz = gxp[H];
        float gxn = gxp[2 * H];

        // every wave polls its OWN quarter of the previous row (1KB each),
        // data-as-flag, no backoff (detection quantization experiment)
        if (step == 0) {
            *(float4*)&hb[wave * 256 + lane * 4] =
                float4{HBIAS, HBIAS, HBIAS, HBIAS};   // biased zero state
        } else {
            const float* tb_prev =
                (step <= SEQ) ? enc_t + (size_t)(step - 1) * H
                              : dec_t + (size_t)(step - SEQ - 1) * H;
            const unsigned long long* src =
                (const unsigned long long*)tb_prev + wave * 128 + lane * 2;
            union { unsigned long long u; float f[2]; } cv[2];
            for (;;) {
                cv[0].u = __hip_atomic_load(src,
                    __ATOMIC_RELAXED, __HIP_MEMORY_SCOPE_AGENT);
                cv[1].u = __hip_atomic_load(src + 1,
                    __ATOMIC_RELAXED, __HIP_MEMORY_SCOPE_AGENT);
                if ((cv[0].f[0] > HVALID) & (cv[0].f[1] > HVALID) &
                    (cv[1].f[0] > HVALID) & (cv[1].f[1] > HVALID)) break;
            }
            *(float4*)&hb[wave * 256 + lane * 4] =
                float4{cv[0].f[0], cv[0].f[1], cv[1].f[0], cv[1].f[1]};
        }
        __syncthreads();   // the ONLY barrier per step

        // dot products over the biased h; rotation keeps register indices
        // compile-time and LDS reads at worst 2-way conflicted (free).
        float a0 = 0.f, a1 = 0.f, a2 = 0.f;
#pragma unroll
        for (int k = 0; k < 16; ++k) {
            float4 h = *(const float4*)&hb[64 * p + 4 * ((k + p) & 15)];
            float4 w0 = wreg[0][k], w1 = wreg[1][k], w2 = wreg[2][k];
            a0 += w0.x * h.x + w0.y * h.y + w0.z * h.z + w0.w * h.w;
            a1 += w1.x * h.x + w1.y * h.y + w1.z * h.z + w1.w * h.w;
            a2 += w2.x * h.x + w2.y * h.y + w2.z * h.z + w2.w * h.w;
        }
        float sr = row16_sum(a0);
        float sz = row16_sum(a1);
        float sn = row16_sum(a2);

        float rg = 1.f / (1.f + expf(-(gxr + sr + br)));
        float zg = 1.f / (1.f + expf(-(gxz + sz + bz)));
        float ng = tanhf(gxn + rg * (sn + bn));
        float hnew = (1.f - zg) * ng + zg * hown;
        hown = hnew;

        if (p == 0)
            __hip_atomic_store(tb_out + myidx, hnew + HBIAS,
                               __ATOMIC_RELAXED, __HIP_MEMORY_SCOPE_AGENT);
    }
}

// ---------- worker GEMM tile (64x64, TK=16) ----------
// MODE 0: A = emb[inputs[m]]            (encoder input GEMM -> gxe)
// MODE 1: A = emb[m==0?0:targets[m-1]]  (decoder input GEMM -> gxd)
// MODE 2: A = dec_t[m] - HBIAS          (projection -> logits)
template <int MODE>
__device__ void gemm_tile(const float* __restrict__ Abase,
                          const int* __restrict__ toks,
                          int m0, int n0,
                          const float* __restrict__ W,
                          const float* __restrict__ bias,
                          float* __restrict__ C, int N,
                          float* __restrict__ sA, float* __restrict__ sB)
{
    const int tid = threadIdx.x;
    const int r = tid >> 2;
    const int c = tid & 3;
    const int tx = tid & 15;
    const int ty = tid >> 4;
    const int m = m0 + r;

    const float* Arow;
    if (MODE == 0)      Arow = Abase + (size_t)toks[m] * H;
    else if (MODE == 1) Arow = Abase + (size_t)(m == 0 ? 0 : toks[m - 1]) * H;
    else                Arow = Abase + (size_t)m * H;
    const float* Brow = W + (size_t)(n0 + r) * H;
    const float abias = (MODE == 2) ? HBIAS : 0.f;

    float acc[4][4] = {};
    for (int k0 = 0; k0 < H; k0 += 16) {
        float4 av = *(const float4*)(Arow + k0 + c * 4);
        float4 bv = *(const float4*)(Brow + k0 + c * 4);
        __syncthreads();
        sA[(c * 4 + 0) * 68 + r] = av.x - abias;
        sA[(c * 4 + 1) * 68 + r] = av.y - abias;
        sA[(c * 4 + 2) * 68 + r] = av.z - abias;
        sA[(c * 4 + 3) * 68 + r] = av.w - abias;
        sB[(c * 4 + 0) * 68 + r] = bv.x;
        sB[(c * 4 + 1) * 68 + r] = bv.y;
        sB[(c * 4 + 2) * 68 + r] = bv.z;
        sB[(c * 4 + 3) * 68 + r] = bv.w;
        __syncthreads();
#pragma unroll
        for (int kk = 0; kk < 16; ++kk) {
            float4 a = *(const float4*)&sA[kk * 68 + ty * 4];
            float4 b = *(const float4*)&sB[kk * 68 + tx * 4];
            float avv[4] = {a.x, a.y, a.z, a.w};
            float bvv[4] = {b.x, b.y, b.z, b.w};
#pragma unroll
            for (int i = 0; i < 4; ++i)
#pragma unroll
                for (int jj = 0; jj < 4; ++jj)
                    acc[i][jj] += avv[i] * bvv[jj];
        }
    }
    float4 bq = *(const float4*)(bias + n0 + tx * 4);
    float bb[4] = {bq.x, bq.y, bq.z, bq.w};
#pragma unroll
    for (int i = 0; i < 4; ++i) {
        float4 o;
        o.x = acc[i][0] + bb[0];
        o.y = acc[i][1] + bb[1];
        o.z = acc[i][2] + bb[2];
        o.w = acc[i][3] + bb[3];
        *(float4*)&C[(size_t)(m0 + ty * 4 + i) * N + n0 + tx * 4] = o;
    }
}

// ---------- worker path: blocks 64..255 ----------
// Acyclic producer/consumer graph (no deadlock under any residency):
// workers -> gx -> rnn; rnn -> dec_t -> workers.
// Phase gxe/gxd: tiles mb-major; per tile __threadfence() (writeback)
// then a per-tile flag. Phase warm: touch pW so projection hits LLC.
// Phase proj: data-as-flag gating on dec_t rows + acquire fence (proven).
__device__ void worker_path(int wid, int tid, float* smem,
    const float* __restrict__ emb,
    const int* __restrict__ inputs, const int* __restrict__ targets,
    const float* __restrict__ eWih, const float* __restrict__ ebih,
    const float* __restrict__ dWih, const float* __restrict__ dbih,
    float* __restrict__ gxe, float* __restrict__ gxd,
    float* __restrict__ fe, float* __restrict__ fd,
    const float* __restrict__ dec_t,
    const float* __restrict__ pW, const float* __restrict__ pb,
    float* __restrict__ out)
{
    float* sA = smem;
    float* sB = smem + 16 * 68;

    // Phase gxe: 8 x 48 tiles, mb-major so m-block 0 completes first
    for (int q = wid; q < 8 * 48; q += NWORK) {
        int mb = q / 48, nb = q % 48;
        gemm_tile<0>(emb, inputs, mb * 64, nb * 64, eWih, ebih,
                     gxe, THREEH, sA, sB);
        __threadfence();   // push tile stores through L2 to LLC
        __syncthreads();   // all waves' stores fenced before flag
        if (tid == 0)
            __hip_atomic_store(fe + mb * 64 + nb, 1.0f,
                               __ATOMIC_RELAXED, __HIP_MEMORY_SCOPE_AGENT);
    }
    // Phase gxd: same for the decoder input GEMM
    for (int q = wid; q < 8 * 48; q += NWORK) {
        int mb = q / 48, nb = q % 48;
        gemm_tile<1>(emb, targets, mb * 64, nb * 64, dWih, dbih,
                     gxd, THREEH, sA, sB);
        __threadfence();
        __syncthreads();
        if (tid == 0)
            __hip_atomic_store(fd + mb * 64 + nb, 1.0f,
                               __ATOMIC_RELAXED, __HIP_MEMORY_SCOPE_AGENT);
    }

    // Phase warm: touch one dword per 128B line of pW
    {
        float acc = 0.f;
        const size_t nlines = (size_t)VOCABN * H / 32;   // 1,024,000
        for (size_t i = (size_t)wid * 256 + tid; i < nlines;
             i += (size_t)NWORK * 256)
            acc += pW[i * 32];
        asm volatile("" :: "v"(acc));   // keep the loads alive (no DCE)
    }

    // Phase proj: logits = (dec_t - HBIAS) @ pW^T + pb   (8 x 500 tiles)
    int cur = -1;
    for (int tt = wid; tt < 8 * 500; tt += NWORK) {
        int mb = tt / 500, nb = tt % 500;
        if (mb != cur) {
            if (tid < 64) {
                const unsigned long long* src =
                    (const unsigned long long*)(dec_t + (size_t)(mb * 64 + 63) * H);
                for (;;) {
                    bool ok = true;
#pragma unroll
                    for (int m = 0; m < 8; ++m) {
                        union { unsigned long long u; float f[2]; } c;
                        c.u = __hip_atomic_load(src + tid + 64 * m,
                            __ATOMIC_RELAXED, __HIP_MEMORY_SCOPE_AGENT);
                        ok &= (c.f[0] > HVALID) & (c.f[1] > HVALID);
                    }
                    if (ok) break;
                    __builtin_amdgcn_s_sleep(64);   // coarse: slack is large
                }
            }
            __syncthreads();
            __builtin_amdgcn_fence(__ATOMIC_ACQUIRE, "agent"); // drop stale L1/L2
            cur = mb;
        }
        gemm_tile<2>(dec_t, nullptr, mb * 64, nb * 64, pW, pb,
                     out, VOCABN, sA, sB);
    }
}

// ---------- fused persistent kernel: 64 rnn blocks + 192 workers ----------
__global__ __launch_bounds__(256, 1) void fused_rnn(
    const float* __restrict__ eWhh, const float* __restrict__ ebhh,
    const float* __restrict__ dWhh, const float* __restrict__ dbhh,
    float* __restrict__ gxe, float* __restrict__ gxd,
    float* __restrict__ enc_t, float* __restrict__ dec_t,
    float* __restrict__ fe, float* __restrict__ fd,
    const float* __restrict__ emb,
    const int* __restrict__ inputs, const int* __restrict__ targets,
    const float* __restrict__ eWih, const float* __restrict__ ebih,
    const float* __restrict__ dWih, const float* __restrict__ dbih,
    const float* __restrict__ pW, const float* __restrict__ pb,
    float* __restrict__ out)
{
    __shared__ float smem[2176];   // rnn: hs[2][1024]; worker: sA/sB [16][68]
    const int b = blockIdx.x;
    if (b < NBLK)
        rnn_path(b, threadIdx.x, smem, eWhh, ebhh, dWhh, dbhh,
                 gxe, gxd, enc_t, dec_t, fe, fd);
    else
        worker_path(b - NBLK, threadIdx.x, smem, emb, inputs, targets,
                    eWih, ebih, dWih, dbih, gxe, gxd, fe, fd,
                    dec_t, pW, pb, out);
}

extern "C" void kernel_launch(void* const* d_in, const int* in_sizes, int n_in,
                              void* d_out, int out_size, void* d_ws, size_t ws_size,
                              hipStream_t stream) {
    const int*   inputs  = (const int*)d_in[0];
    const int*   targets = (const int*)d_in[1];
    const float* emb     = (const float*)d_in[2];
    const float* eWih    = (const float*)d_in[3];
    const float* eWhh    = (const float*)d_in[4];
    const float* ebih    = (const float*)d_in[5];
    const float* ebhh    = (const float*)d_in[6];
    const float* dWih    = (const float*)d_in[7];
    const float* dWhh    = (const float*)d_in[8];
    const float* dbih    = (const float*)d_in[9];
    const float* dbhh    = (const float*)d_in[10];
    const float* pW      = (const float*)d_in[11];
    const float* pb      = (const float*)d_in[12];
    float* out = (float*)d_out;

    float* gxe   = (float*)d_ws;                  // [512][3072]
    float* gxd   = gxe + (size_t)SEQ * THREEH;    // [512][3072]
    float* enc_t = gxd + (size_t)SEQ * THREEH;    // [512][1024] biased
    float* dec_t = enc_t + (size_t)SEQ * H;       // [512][1024] biased
    float* fe    = dec_t + (size_t)SEQ * H;       // [8][64] gxe tile flags
    float* fd    = fe + 8 * 64;                   // [8][64] gxd tile flags

    // single fused launch: 64 recurrence blocks + 192 GEMM workers
    fused_rnn<<<NBLK + NWORK, 256, 0, stream>>>(
        eWhh, ebhh, dWhh, dbhh, gxe, gxd, enc_t, dec_t, fe, fd,
        emb, inputs, targets, eWih, ebih, dWih, dbih, pW, pb, out);
}